// Round 18
// baseline (670.781 us; speedup 1.0000x reference)
//
#include <hip/hip_runtime.h>
#include <hip/hip_bf16.h>
#include <math.h>

#define NNODE 200000
#define NEDGE 1000000
#define HEDGE 500000

typedef __attribute__((ext_vector_type(8))) short bf16x8;
typedef __attribute__((ext_vector_type(4))) float f32x4;

// ---- float <-> bf16 (RNE) ----
__device__ __forceinline__ unsigned short f2bf(float f) {  // manual RNE (prep only)
  unsigned u = __float_as_uint(f);
  unsigned r = (u + 0x7fffu + ((u >> 16) & 1u)) >> 16;
  return (unsigned short)r;
}
__device__ __forceinline__ unsigned short f2bf_hw(float f) {  // HW cvt (hot path)
  __hip_bfloat16 h = __float2bfloat16(f);
  return __builtin_bit_cast(unsigned short, h);
}
__device__ __forceinline__ float bf2f(unsigned short h) {
  return __uint_as_float(((unsigned)h) << 16);
}

// ---- f16 x4 pack/unpack (aggr/lse intermediates). LESSON (r15/r16): the
// 3.3x k_gather blowup was ext_vector f32x4[8] register-cache arrays
// scratch-allocating (rule #20), NOT nontemporal hints. float4 arrays only.
__device__ __forceinline__ uint2 pack_h4(float x, float y, float z, float w) {
  unsigned short a = __builtin_bit_cast(unsigned short, (_Float16)x);
  unsigned short b = __builtin_bit_cast(unsigned short, (_Float16)y);
  unsigned short c = __builtin_bit_cast(unsigned short, (_Float16)z);
  unsigned short d = __builtin_bit_cast(unsigned short, (_Float16)w);
  uint2 r;
  r.x = (unsigned)a | ((unsigned)b << 16);
  r.y = (unsigned)c | ((unsigned)d << 16);
  return r;
}
__device__ __forceinline__ float4 unpack_h4(uint2 p) {
  float4 v;
  v.x = (float)__builtin_bit_cast(_Float16, (unsigned short)(p.x & 0xffff));
  v.y = (float)__builtin_bit_cast(_Float16, (unsigned short)(p.x >> 16));
  v.z = (float)__builtin_bit_cast(_Float16, (unsigned short)(p.y & 0xffff));
  v.w = (float)__builtin_bit_cast(_Float16, (unsigned short)(p.y >> 16));
  return v;
}

// ======================= CSR build =======================
__global__ void k_deg(const int* __restrict__ ei, const int* __restrict__ c2li,
                      int* __restrict__ degA, int* __restrict__ degB) {
  int j = blockIdx.x * 256 + threadIdx.x;
  if (j < NEDGE) atomicAdd(&degA[ei[2 * j + 1]], 1);
  if (j < HEDGE) {
    int jj = c2li[j];
    atomicAdd(&degB[ei[2 * jj]], 1);
  }
}

// Wave-aggregated CSR range allocator (bucket order irrelevant for gathers).
__global__ void k_alloc(const int* __restrict__ degA, int* __restrict__ offA, int* __restrict__ curA,
                        const int* __restrict__ degB, int* __restrict__ offB, int* __restrict__ curB,
                        int* __restrict__ cursors) {
  int i = blockIdx.x * 256 + threadIdx.x;
  int lane = threadIdx.x & 63;
  bool act = i < NNODE;
#pragma unroll
  for (int which = 0; which < 2; ++which) {
    const int* deg = which ? degB : degA;
    int* off = which ? offB : offA;
    int* cur = which ? curB : curA;
    int d = act ? deg[i] : 0;
    int incl = d;
#pragma unroll
    for (int s = 1; s < 64; s <<= 1) {
      int v = __shfl_up(incl, s, 64);
      if (lane >= s) incl += v;
    }
    int base = 0;
    if (lane == 63) base = atomicAdd(&cursors[which], incl);
    base = __shfl(base, 63, 64);
    if (act) {
      int o = base + incl - d;
      off[i] = o;
      cur[i] = o;
    }
  }
}

__global__ void k_fill(const int* __restrict__ ei, const int* __restrict__ c2li,
                       int* __restrict__ curA, int* __restrict__ listA,
                       int* __restrict__ curB, int* __restrict__ listB) {
  int j = blockIdx.x * 256 + threadIdx.x;
  if (j < NEDGE) {
    int d = ei[2 * j + 1];
    int s = atomicAdd(&curA[d], 1);
    listA[s] = j;
  }
  if (j < HEDGE) {
    int jj = c2li[j];
    int sn = ei[2 * jj], dn = ei[2 * jj + 1];
    int s = atomicAdd(&curB[sn], 1);
    listB[s] = dn;
  }
}

// ---- gather: one 16-LANE GROUP per node; pure register reduce ----
__global__ void k_gather(const int* __restrict__ offA, const int* __restrict__ degA,
                         const int* __restrict__ listA,
                         const int* __restrict__ offB, const int* __restrict__ degB,
                         const int* __restrict__ listB,
                         const float* __restrict__ emb,
                         uint2* __restrict__ aggrH, uint2* __restrict__ lseH, int gN) {
  int tid = threadIdx.x;
  int l16 = tid & 15, grp = tid >> 4;  // 16 groups per block
  bool taskA = blockIdx.x < gN;
  int node = (taskA ? blockIdx.x : blockIdx.x - gN) * 16 + grp;
  if (node >= NNODE) return;
  if (taskA) {
    int o = offA[node], n = degA[node];
    float4 acc = {0.f, 0.f, 0.f, 0.f};
    if (n <= 8) {
      int e[8];
#pragma unroll
      for (int i = 0; i < 8; ++i) e[i] = (i < n) ? listA[o + i] : -1;
      float4 v[8];
#pragma unroll
      for (int i = 0; i < 8; ++i) {
        v[i] = (float4){0.f, 0.f, 0.f, 0.f};
        if (e[i] >= 0) v[i] = *(const float4*)(emb + (size_t)e[i] * 64 + 4 * l16);
      }
#pragma unroll
      for (int i = 0; i < 8; ++i) {
        acc.x += v[i].x; acc.y += v[i].y; acc.z += v[i].z; acc.w += v[i].w;
      }
    } else {
      float4 a0 = {0.f, 0.f, 0.f, 0.f}, a1 = a0, a2 = a0, a3 = a0;
      for (int i = 0; i < n; i += 4) {
        int e0 = listA[o + i];
        int e1 = (i + 1 < n) ? listA[o + i + 1] : -1;
        int e2 = (i + 2 < n) ? listA[o + i + 2] : -1;
        int e3 = (i + 3 < n) ? listA[o + i + 3] : -1;
        float4 v0 = *(const float4*)(emb + (size_t)e0 * 64 + 4 * l16);
        a0.x += v0.x; a0.y += v0.y; a0.z += v0.z; a0.w += v0.w;
        if (e1 >= 0) {
          float4 v = *(const float4*)(emb + (size_t)e1 * 64 + 4 * l16);
          a1.x += v.x; a1.y += v.y; a1.z += v.z; a1.w += v.w;
        }
        if (e2 >= 0) {
          float4 v = *(const float4*)(emb + (size_t)e2 * 64 + 4 * l16);
          a2.x += v.x; a2.y += v.y; a2.z += v.z; a2.w += v.w;
        }
        if (e3 >= 0) {
          float4 v = *(const float4*)(emb + (size_t)e3 * 64 + 4 * l16);
          a3.x += v.x; a3.y += v.y; a3.z += v.z; a3.w += v.w;
        }
      }
      acc.x = (a0.x + a1.x) + (a2.x + a3.x);
      acc.y = (a0.y + a1.y) + (a2.y + a3.y);
      acc.z = (a0.z + a1.z) + (a2.z + a3.z);
      acc.w = (a0.w + a1.w) + (a2.w + a3.w);
    }
    aggrH[(size_t)node * 16 + l16] = pack_h4(acc.x, acc.y, acc.z, acc.w);  // empty -> 0
  } else {
    int o = offB[node], n = degB[node];
    if (n == 0) return;  // lse only read at nodes with c2l out-edges
    float rx, ry, rz, rw;
    if (n <= 8) {
      float4 v[8];
#pragma unroll
      for (int i = 0; i < 8; ++i) {
        v[i] = (float4){-INFINITY, -INFINITY, -INFINITY, -INFINITY};
        if (i < n) {
          int d = listB[o + i];
          v[i] = *(const float4*)(emb + (size_t)d * 64 + 4 * l16);
        }
      }
      float4 m = v[0];
#pragma unroll
      for (int i = 1; i < 8; ++i) {
        m.x = fmaxf(m.x, v[i].x); m.y = fmaxf(m.y, v[i].y);
        m.z = fmaxf(m.z, v[i].z); m.w = fmaxf(m.w, v[i].w);
      }
      float4 s = {0.f, 0.f, 0.f, 0.f};
#pragma unroll
      for (int i = 0; i < 8; ++i) {  // exp(-inf - m) = 0 for empty slots
        s.x += __expf(v[i].x - m.x); s.y += __expf(v[i].y - m.y);
        s.z += __expf(v[i].z - m.z); s.w += __expf(v[i].w - m.w);
      }
      rx = __logf(s.x) + m.x; ry = __logf(s.y) + m.y;
      rz = __logf(s.z) + m.z; rw = __logf(s.w) + m.w;
    } else {
      float4 m = {-INFINITY, -INFINITY, -INFINITY, -INFINITY};
      for (int i = 0; i < n; i += 2) {
        int d0 = listB[o + i];
        int d1 = (i + 1 < n) ? listB[o + i + 1] : -1;
        float4 v0 = *(const float4*)(emb + (size_t)d0 * 64 + 4 * l16);
        m.x = fmaxf(m.x, v0.x); m.y = fmaxf(m.y, v0.y);
        m.z = fmaxf(m.z, v0.z); m.w = fmaxf(m.w, v0.w);
        if (d1 >= 0) {
          float4 v = *(const float4*)(emb + (size_t)d1 * 64 + 4 * l16);
          m.x = fmaxf(m.x, v.x); m.y = fmaxf(m.y, v.y);
          m.z = fmaxf(m.z, v.z); m.w = fmaxf(m.w, v.w);
        }
      }
      float4 s = {0.f, 0.f, 0.f, 0.f};
      for (int i = 0; i < n; i += 2) {
        int d0 = listB[o + i];
        int d1 = (i + 1 < n) ? listB[o + i + 1] : -1;
        float4 v0 = *(const float4*)(emb + (size_t)d0 * 64 + 4 * l16);
        s.x += __expf(v0.x - m.x); s.y += __expf(v0.y - m.y);
        s.z += __expf(v0.z - m.z); s.w += __expf(v0.w - m.w);
        if (d1 >= 0) {
          float4 v = *(const float4*)(emb + (size_t)d1 * 64 + 4 * l16);
          s.x += __expf(v.x - m.x); s.y += __expf(v.y - m.y);
          s.z += __expf(v.z - m.z); s.w += __expf(v.w - m.w);
        }
      }
      rx = __logf(s.x) + m.x; ry = __logf(s.y) + m.y;
      rz = __logf(s.z) + m.z; rw = __logf(s.w) + m.w;
    }
    lseH[(size_t)node * 16 + l16] = pack_h4(rx, ry, rz, rw);  // s >= 1 (max attained)
  }
}

// ======================= weight prep =======================
// Frag-ordered bf16 hi/lo. value = W[32s + 8*(lane>>4) + j][16c + (lane&15)].
// Elem offsets: l2c L1/L2/L3: 0/4096/8192; merge_W0: 12288 (K=128);
// merge_W L1/L2: 20480/24576; c2l L1/L2/L3: 28672/32768/36864. Total 40960.
__global__ void k_prepw(const float* __restrict__ l2cW, const float* __restrict__ mW0,
                        const float* __restrict__ mW, const float* __restrict__ c2lW,
                        unsigned short* __restrict__ WH, unsigned short* __restrict__ WL) {
  int tid = blockIdx.x * 256 + threadIdx.x;
  if (tid >= 40960) return;
  const float* src;
  int base;
  if (tid < 12288) {
    int m = tid / 4096; src = l2cW + m * 4096; base = m * 4096;
  } else if (tid < 20480) {
    src = mW0; base = 12288;
  } else if (tid < 28672) {
    int m = (tid - 20480) / 4096; src = mW + m * 4096; base = 20480 + m * 4096;
  } else {
    int m = (tid - 28672) / 4096; src = c2lW + m * 4096; base = 28672 + m * 4096;
  }
  int local = tid - base;
  int f = local >> 9;           // frag id = s*4+c
  int l = (local >> 3) & 63;    // lane
  int j = local & 7;            // elem
  int s = f >> 2, c = f & 3;
  int k = 32 * s + 8 * (l >> 4) + j;
  int col = 16 * c + (l & 15);
  float v = src[k * 64 + col];
  unsigned short hh = f2bf(v);
  WH[tid] = hh;
  WL[tid] = f2bf(v - bf2f(hh));
}

// ======================= MFMA MLP machinery =======================
// Wave-private LDS tile xs[16 rows][64 cols] f32, XOR-swizzled:
//   dword(row,col) = row*64 + (((col>>2) ^ row) & 15)*4 + (col & 3)
// (4-dword groups stay contiguous -> float4/b128 access legal.)
// 1024-thread blocks (16 waves): 80KB LDS -> 2 blocks/CU.

__device__ __forceinline__ void split8(float t0, float t1, float t2, float t3,
                                       float t4, float t5, float t6, float t7,
                                       bf16x8& ah, bf16x8& al) {
  unsigned short h;
  h = f2bf_hw(t0); ah[0] = (short)h; al[0] = (short)f2bf_hw(t0 - bf2f(h));
  h = f2bf_hw(t1); ah[1] = (short)h; al[1] = (short)f2bf_hw(t1 - bf2f(h));
  h = f2bf_hw(t2); ah[2] = (short)h; al[2] = (short)f2bf_hw(t2 - bf2f(h));
  h = f2bf_hw(t3); ah[3] = (short)h; al[3] = (short)f2bf_hw(t3 - bf2f(h));
  h = f2bf_hw(t4); ah[4] = (short)h; al[4] = (short)f2bf_hw(t4 - bf2f(h));
  h = f2bf_hw(t5); ah[5] = (short)h; al[5] = (short)f2bf_hw(t5 - bf2f(h));
  h = f2bf_hw(t6); ah[6] = (short)h; al[6] = (short)f2bf_hw(t6 - bf2f(h));
  h = f2bf_hw(t7); ah[7] = (short)h; al[7] = (short)f2bf_hw(t7 - bf2f(h));
}

// Stage one layer's 4096-elem hi+lo weights (16KB) with 1024 threads.
__device__ __forceinline__ void stage_w(const unsigned short* __restrict__ WH,
                                        const unsigned short* __restrict__ WL, int off,
                                        unsigned short* lwh, unsigned short* lwl, int tid) {
  __syncthreads();  // all waves done with previous layer's weights
  if (tid < 512) ((uint4*)lwh)[tid] = ((const uint4*)(WH + off))[tid];
  else           ((uint4*)lwl)[tid - 512] = ((const uint4*)(WL + off))[tid - 512];
  __syncthreads();
}

__device__ __forceinline__ void acc_init(const float* __restrict__ bias, int col15,
                                         f32x4 (&acc)[4]) {
#pragma unroll
  for (int c = 0; c < 4; ++c) {
    float bv = bias[16 * c + col15];
    acc[c] = (f32x4){bv, bv, bv, bv};
  }
}

__device__ __forceinline__ void acc_relu(f32x4 (&acc)[4]) {
#pragma unroll
  for (int c = 0; c < 4; ++c)
#pragma unroll
    for (int r = 0; r < 4; ++r) acc[c][r] = fmaxf(acc[c][r], 0.f);
}

// Accumulate 2 K-slices (K=64) from LDS weights. FLIPALL: partner row (t^1).
// Split-bf16: acc += al*wh + ah*wl + ah*wh (misses only lo*lo ~ 2^-18).
template <bool FLIPALL>
__device__ __forceinline__ void mfma_accum(const float* xw, int lane,
                                           const unsigned short* lwh,
                                           const unsigned short* lwl, f32x4 (&acc)[4]) {
  int col15 = lane & 15, hq = lane >> 4;
  int arow = FLIPALL ? (col15 ^ 1) : col15;
  const float* xr = xw + arow * 64;
#pragma unroll
  for (int s = 0; s < 2; ++s) {
    float4 A0 = *(const float4*)(xr + ((((8 * s + 2 * hq + 0) ^ arow) & 15) << 2));
    float4 A1 = *(const float4*)(xr + ((((8 * s + 2 * hq + 1) ^ arow) & 15) << 2));
    bf16x8 ah, al;
    split8(A0.x, A0.y, A0.z, A0.w, A1.x, A1.y, A1.z, A1.w, ah, al);
#pragma unroll
    for (int c = 0; c < 4; ++c) {
      bf16x8 wh = *(const bf16x8*)(lwh + ((s * 4 + c) * 64 + lane) * 8);
      bf16x8 wl = *(const bf16x8*)(lwl + ((s * 4 + c) * 64 + lane) * 8);
      acc[c] = __builtin_amdgcn_mfma_f32_16x16x32_bf16(al, wh, acc[c], 0, 0, 0);
      acc[c] = __builtin_amdgcn_mfma_f32_16x16x32_bf16(ah, wl, acc[c], 0, 0, 0);
      acc[c] = __builtin_amdgcn_mfma_f32_16x16x32_bf16(ah, wh, acc[c], 0, 0, 0);
    }
  }
}

__device__ __forceinline__ void commitA(float* xw, int lane, const f32x4 (&acc)[4]) {
  int col15 = lane & 15, hq = lane >> 4;
#pragma unroll
  for (int c = 0; c < 4; ++c)
#pragma unroll
    for (int r = 0; r < 4; ++r) {
      int row = 4 * hq + r, col = 16 * c + col15;
      xw[row * 64 + ((((col >> 2) ^ row) & 15) << 2) + (col & 3)] = acc[c][r];
    }
}

// ---- fused MLP kernel: blocks [0, nL) run l2c, blocks [nL, 2*nL) run c2l ----
__global__ void __launch_bounds__(1024, 8)
k_mlp(const int* __restrict__ ei, const int* __restrict__ l2ci, const int* __restrict__ c2li,
      const float* __restrict__ emb, const uint2* __restrict__ aggrH, const uint2* __restrict__ lseH,
      const unsigned short* __restrict__ WH, const unsigned short* __restrict__ WL,
      const float* __restrict__ l2cb, const float* __restrict__ mb0,
      const float* __restrict__ mb, const float* __restrict__ c2lb,
      float* __restrict__ out, int nL) {
  __shared__ float xs[16][1024];          // 64 KB
  __shared__ unsigned short lwh[4096];    // 8 KB
  __shared__ unsigned short lwl[4096];    // 8 KB
  int tid = threadIdx.x;
  int lane = tid & 63, w = tid >> 6;      // 16 waves
  float* xw = xs[w];
  bool isL = (int)blockIdx.x < nL;
  int bid = isL ? blockIdx.x : blockIdx.x - nL;
  const int* idx = isL ? l2ci : c2li;
  int rbase = (bid * 16 + w) * 16;
  int col15 = lane & 15, hq = lane >> 4;
  int rin = min(rbase + col15, HEDGE - 1);
  int j = idx[rin];
  int sN = ei[2 * j], dN = ei[2 * j + 1];
  const uint2* ap = (isL ? aggrH : lseH) + (size_t)sN * 16 + 4 * hq;
  const float* ep = emb + (size_t)dN * 64 + 16 * hq;
#pragma unroll
  for (int q = 0; q < 4; ++q) {
    float4 a = unpack_h4(ap[q]);
    float4 e = *(const float4*)(ep + 4 * q);
    float4 v = {a.x - e.x, a.y - e.y, a.z - e.z, a.w - e.w};
    *(float4*)(xw + col15 * 64 + ((((4 * hq + q) ^ col15) & 15) << 2)) = v;
  }
  f32x4 acc[4];
  if (isL) {
    stage_w(WH, WL, 0, lwh, lwl, tid);
    acc_init(l2cb, col15, acc);       mfma_accum<false>(xw, lane, lwh, lwl, acc);
    acc_relu(acc);                    commitA(xw, lane, acc);
    stage_w(WH, WL, 4096, lwh, lwl, tid);
    acc_init(l2cb + 64, col15, acc);  mfma_accum<false>(xw, lane, lwh, lwl, acc);
    acc_relu(acc);                    commitA(xw, lane, acc);
    stage_w(WH, WL, 8192, lwh, lwl, tid);
    acc_init(l2cb + 128, col15, acc); mfma_accum<false>(xw, lane, lwh, lwl, acc);
    commitA(xw, lane, acc);           // msg (no relu)
    stage_w(WH, WL, 12288, lwh, lwl, tid);   // merge own half
    acc_init(mb0, col15, acc);        mfma_accum<false>(xw, lane, lwh, lwl, acc);
    stage_w(WH, WL, 16384, lwh, lwl, tid);   // merge flip half
    mfma_accum<true>(xw, lane, lwh, lwl, acc);
    acc_relu(acc);                    commitA(xw, lane, acc);
    stage_w(WH, WL, 20480, lwh, lwl, tid);
    acc_init(mb, col15, acc);         mfma_accum<false>(xw, lane, lwh, lwl, acc);
    acc_relu(acc);                    commitA(xw, lane, acc);
    stage_w(WH, WL, 24576, lwh, lwl, tid);
    acc_init(mb + 64, col15, acc);    mfma_accum<false>(xw, lane, lwh, lwl, acc);
  } else {
    stage_w(WH, WL, 28672, lwh, lwl, tid);
    acc_init(c2lb, col15, acc);       mfma_accum<false>(xw, lane, lwh, lwl, acc);
    acc_relu(acc);                    commitA(xw, lane, acc);
    stage_w(WH, WL, 32768, lwh, lwl, tid);
    acc_init(c2lb + 64, col15, acc);  mfma_accum<false>(xw, lane, lwh, lwl, acc);
    acc_relu(acc);                    commitA(xw, lane, acc);
    stage_w(WH, WL, 36864, lwh, lwl, tid);
    acc_init(c2lb + 128, col15, acc); mfma_accum<false>(xw, lane, lwh, lwl, acc);
  }
  // ---- vectorized epilogue: acc -> LDS (wave-private, no barrier) -> dense
  // float4 stores. Lane mapping per q: row = 4q + hq, cols 4*col15..+3 ->
  // one store instruction covers 4 complete 256B rows; since l2c/c2l index
  // arrays are sequential, consecutive rows are adjacent -> 1KB bursts.
  // (Replaces 16 scalar stores/thread; round-17 WRITE was 329MB vs 256 ideal.)
  commitA(xw, lane, acc);
#pragma unroll
  for (int q = 0; q < 4; ++q) {
    int row = 4 * q + hq;
    int rr2 = rbase + row;
    if (rr2 < HEDGE) {
      int j2 = idx[rr2];
      const float* src4 = xw + row * 64 + (((col15 ^ row) & 15) << 2);
      float4 v = *(const float4*)src4;
      *(float4*)(out + (size_t)j2 * 64 + 4 * col15) = v;
    }
  }
}

extern "C" void kernel_launch(void* const* d_in, const int* in_sizes, int n_in,
                              void* d_out, int out_size, void* d_ws, size_t ws_size,
                              hipStream_t stream) {
  const int* ei = (const int*)d_in[0];
  const int* l2ci = (const int*)d_in[1];
  const int* c2li = (const int*)d_in[2];
  const float* emb = (const float*)d_in[3];
  const float* l2cW = (const float*)d_in[4];
  const float* l2cb = (const float*)d_in[5];
  const float* c2lW = (const float*)d_in[6];
  const float* c2lb = (const float*)d_in[7];
  const float* mW0 = (const float*)d_in[8];
  const float* mb0 = (const float*)d_in[9];
  const float* mW = (const float*)d_in[10];
  const float* mb = (const float*)d_in[11];
  float* out = (float*)d_out;

  char* ws = (char*)d_ws;
  const size_t NBH = (size_t)NNODE * 64 * 2;  // 25.6 MB per f16 node-buffer
  uint2* aggrH = (uint2*)ws;
  uint2* lseH = (uint2*)(ws + NBH);
  unsigned short* WH = (unsigned short*)(ws + 2 * NBH);
  unsigned short* WL = WH + 40960;  // 163840 B total for weights
  char* p = ws + 2 * NBH + 163840;
  int* degA = (int*)p; p += NNODE * 4;
  int* degB = (int*)p; p += NNODE * 4;
  int* cursors = (int*)p; p += 2 * 4;
  int* offA = (int*)p; p += NNODE * 4;
  int* offB = (int*)p; p += NNODE * 4;
  int* curA = (int*)p; p += NNODE * 4;
  int* curB = (int*)p; p += NNODE * 4;
  int* listA = (int*)p; p += (size_t)NEDGE * 4;
  int* listB = (int*)p; p += (size_t)HEDGE * 4;

  hipMemsetAsync(degA, 0, (2 * (size_t)NNODE + 2) * 4, stream);  // degA,degB,cursors

  dim3 B(256);
  int gE = (NEDGE + 255) / 256;
  k_deg<<<gE, B, 0, stream>>>(ei, c2li, degA, degB);
  k_alloc<<<(NNODE + 255) / 256, B, 0, stream>>>(degA, offA, curA, degB, offB, curB, cursors);
  k_fill<<<gE, B, 0, stream>>>(ei, c2li, curA, listA, curB, listB);
  k_prepw<<<160, B, 0, stream>>>(l2cW, mW0, mW, c2lW, WH, WL);
  int gN = (NNODE + 15) / 16;  // 16 nodes per block (one per 16-lane group)
  k_gather<<<2 * gN, B, 0, stream>>>(offA, degA, listA, offB, degB, listB, emb, aggrH, lseH, gN);
  int nL = (HEDGE + 255) / 256;  // 256 edges per 1024-thread block
  k_mlp<<<2 * nL, 1024, 0, stream>>>(ei, l2ci, c2li, emb, aggrH, lseH, WH, WL,
                                     l2cb, mb0, mb, c2lb, out, nL);
}

// Round 19
// 562.664 us; speedup vs baseline: 1.1922x; 1.1922x over previous
//
#include <hip/hip_runtime.h>
#include <hip/hip_bf16.h>
#include <math.h>

#define NNODE 200000
#define NEDGE 1000000
#define HEDGE 500000

typedef __attribute__((ext_vector_type(8))) short bf16x8;
typedef __attribute__((ext_vector_type(4))) float f32x4;

// ---- float <-> bf16 (RNE) ----
__device__ __forceinline__ unsigned short f2bf(float f) {  // manual RNE (prep only)
  unsigned u = __float_as_uint(f);
  unsigned r = (u + 0x7fffu + ((u >> 16) & 1u)) >> 16;
  return (unsigned short)r;
}
__device__ __forceinline__ unsigned short f2bf_hw(float f) {  // HW cvt (hot path)
  __hip_bfloat16 h = __float2bfloat16(f);
  return __builtin_bit_cast(unsigned short, h);
}
__device__ __forceinline__ float bf2f(unsigned short h) {
  return __uint_as_float(((unsigned)h) << 16);
}

// ---- f16 x4 pack/unpack. LESSONS: (r15/r16) ext_vector f32x4[8] arrays
// scratch-allocate (rule #20) -> float4 arrays only. (r18) LDS-roundtrip
// vectorized out-epilogue DOUBLED write traffic -> keep scalar out stores.
__device__ __forceinline__ uint2 pack_h4(float x, float y, float z, float w) {
  unsigned short a = __builtin_bit_cast(unsigned short, (_Float16)x);
  unsigned short b = __builtin_bit_cast(unsigned short, (_Float16)y);
  unsigned short c = __builtin_bit_cast(unsigned short, (_Float16)z);
  unsigned short d = __builtin_bit_cast(unsigned short, (_Float16)w);
  uint2 r;
  r.x = (unsigned)a | ((unsigned)b << 16);
  r.y = (unsigned)c | ((unsigned)d << 16);
  return r;
}
__device__ __forceinline__ float4 unpack_h4(uint2 p) {
  float4 v;
  v.x = (float)__builtin_bit_cast(_Float16, (unsigned short)(p.x & 0xffff));
  v.y = (float)__builtin_bit_cast(_Float16, (unsigned short)(p.x >> 16));
  v.z = (float)__builtin_bit_cast(_Float16, (unsigned short)(p.y & 0xffff));
  v.w = (float)__builtin_bit_cast(_Float16, (unsigned short)(p.y >> 16));
  return v;
}

// ======================= CSR build =======================
__global__ void k_deg(const int* __restrict__ ei, const int* __restrict__ c2li,
                      int* __restrict__ degA, int* __restrict__ degB) {
  int j = blockIdx.x * 256 + threadIdx.x;
  if (j < NEDGE) atomicAdd(&degA[ei[2 * j + 1]], 1);
  if (j < HEDGE) {
    int jj = c2li[j];
    atomicAdd(&degB[ei[2 * jj]], 1);
  }
}

// Wave-aggregated CSR range allocator (bucket order irrelevant for gathers).
__global__ void k_alloc(const int* __restrict__ degA, int* __restrict__ offA, int* __restrict__ curA,
                        const int* __restrict__ degB, int* __restrict__ offB, int* __restrict__ curB,
                        int* __restrict__ cursors) {
  int i = blockIdx.x * 256 + threadIdx.x;
  int lane = threadIdx.x & 63;
  bool act = i < NNODE;
#pragma unroll
  for (int which = 0; which < 2; ++which) {
    const int* deg = which ? degB : degA;
    int* off = which ? offB : offA;
    int* cur = which ? curB : curA;
    int d = act ? deg[i] : 0;
    int incl = d;
#pragma unroll
    for (int s = 1; s < 64; s <<= 1) {
      int v = __shfl_up(incl, s, 64);
      if (lane >= s) incl += v;
    }
    int base = 0;
    if (lane == 63) base = atomicAdd(&cursors[which], incl);
    base = __shfl(base, 63, 64);
    if (act) {
      int o = base + incl - d;
      off[i] = o;
      cur[i] = o;
    }
  }
}

__global__ void k_fill(const int* __restrict__ ei, const int* __restrict__ c2li,
                       int* __restrict__ curA, int* __restrict__ listA,
                       int* __restrict__ curB, int* __restrict__ listB) {
  int j = blockIdx.x * 256 + threadIdx.x;
  if (j < NEDGE) {
    int d = ei[2 * j + 1];
    int s = atomicAdd(&curA[d], 1);
    listA[s] = j;
  }
  if (j < HEDGE) {
    int jj = c2li[j];
    int sn = ei[2 * jj], dn = ei[2 * jj + 1];
    int s = atomicAdd(&curB[sn], 1);
    listB[s] = dn;
  }
}

// ---- gather v4: task A = 8-LANE groups (32 nodes/block, 2x load chains
// in flight vs 16-lane; lane l8 owns cols {4*l8..+3} U {32+4*l8..+3} so
// each row = 2 fully-coalesced 128B-line loads). Task B = 16-lane groups
// (exp-heavy, rows hit the cached 51MB slice). launch_bounds(256,4) caps
// VGPR at 128 so the float4 v0[8]+v1[8] arrays (64 VGPR) stay in registers.
__global__ void __launch_bounds__(256, 4)
k_gather(const int* __restrict__ offA, const int* __restrict__ degA,
         const int* __restrict__ listA,
         const int* __restrict__ offB, const int* __restrict__ degB,
         const int* __restrict__ listB,
         const float* __restrict__ emb,
         uint2* __restrict__ aggrH, uint2* __restrict__ lseH, int gNA) {
  int tid = threadIdx.x;
  bool taskA = blockIdx.x < gNA;
  if (taskA) {
    int l8 = tid & 7, grp = tid >> 3;  // 32 groups per block
    int node = blockIdx.x * 32 + grp;
    if (node >= NNODE) return;
    int o = offA[node], n = degA[node];
    float4 acc0 = {0.f, 0.f, 0.f, 0.f}, acc1 = {0.f, 0.f, 0.f, 0.f};
    if (n <= 8) {
      int e[8];
#pragma unroll
      for (int i = 0; i < 8; ++i) e[i] = (i < n) ? listA[o + i] : -1;
      float4 v0[8], v1[8];
#pragma unroll
      for (int i = 0; i < 8; ++i) {
        v0[i] = (float4){0.f, 0.f, 0.f, 0.f};
        v1[i] = (float4){0.f, 0.f, 0.f, 0.f};
        if (e[i] >= 0) {
          const float* r = emb + (size_t)e[i] * 64;
          v0[i] = *(const float4*)(r + 4 * l8);
          v1[i] = *(const float4*)(r + 32 + 4 * l8);
        }
      }
#pragma unroll
      for (int i = 0; i < 8; ++i) {
        acc0.x += v0[i].x; acc0.y += v0[i].y; acc0.z += v0[i].z; acc0.w += v0[i].w;
        acc1.x += v1[i].x; acc1.y += v1[i].y; acc1.z += v1[i].z; acc1.w += v1[i].w;
      }
    } else {
      for (int i = 0; i < n; i += 2) {
        int e0 = listA[o + i];
        int e1 = (i + 1 < n) ? listA[o + i + 1] : -1;
        const float* r0 = emb + (size_t)e0 * 64;
        float4 a = *(const float4*)(r0 + 4 * l8);
        float4 b = *(const float4*)(r0 + 32 + 4 * l8);
        acc0.x += a.x; acc0.y += a.y; acc0.z += a.z; acc0.w += a.w;
        acc1.x += b.x; acc1.y += b.y; acc1.z += b.z; acc1.w += b.w;
        if (e1 >= 0) {
          const float* r1 = emb + (size_t)e1 * 64;
          float4 c = *(const float4*)(r1 + 4 * l8);
          float4 d = *(const float4*)(r1 + 32 + 4 * l8);
          acc0.x += c.x; acc0.y += c.y; acc0.z += c.z; acc0.w += c.w;
          acc1.x += d.x; acc1.y += d.y; acc1.z += d.z; acc1.w += d.w;
        }
      }
    }
    aggrH[(size_t)node * 16 + l8] = pack_h4(acc0.x, acc0.y, acc0.z, acc0.w);
    aggrH[(size_t)node * 16 + 8 + l8] = pack_h4(acc1.x, acc1.y, acc1.z, acc1.w);
  } else {
    int l16 = tid & 15, grp = tid >> 4;  // 16 groups per block
    int node = (blockIdx.x - gNA) * 16 + grp;
    if (node >= NNODE) return;
    int o = offB[node], n = degB[node];
    if (n == 0) return;  // lse only read at nodes with c2l out-edges
    float rx, ry, rz, rw;
    if (n <= 8) {
      float4 v[8];
#pragma unroll
      for (int i = 0; i < 8; ++i) {
        v[i] = (float4){-INFINITY, -INFINITY, -INFINITY, -INFINITY};
        if (i < n) {
          int d = listB[o + i];
          v[i] = *(const float4*)(emb + (size_t)d * 64 + 4 * l16);
        }
      }
      float4 m = v[0];
#pragma unroll
      for (int i = 1; i < 8; ++i) {
        m.x = fmaxf(m.x, v[i].x); m.y = fmaxf(m.y, v[i].y);
        m.z = fmaxf(m.z, v[i].z); m.w = fmaxf(m.w, v[i].w);
      }
      float4 s = {0.f, 0.f, 0.f, 0.f};
#pragma unroll
      for (int i = 0; i < 8; ++i) {  // exp(-inf - m) = 0 for empty slots
        s.x += __expf(v[i].x - m.x); s.y += __expf(v[i].y - m.y);
        s.z += __expf(v[i].z - m.z); s.w += __expf(v[i].w - m.w);
      }
      rx = __logf(s.x) + m.x; ry = __logf(s.y) + m.y;
      rz = __logf(s.z) + m.z; rw = __logf(s.w) + m.w;
    } else {
      float4 m = {-INFINITY, -INFINITY, -INFINITY, -INFINITY};
      for (int i = 0; i < n; i += 2) {
        int d0 = listB[o + i];
        int d1 = (i + 1 < n) ? listB[o + i + 1] : -1;
        float4 v0 = *(const float4*)(emb + (size_t)d0 * 64 + 4 * l16);
        m.x = fmaxf(m.x, v0.x); m.y = fmaxf(m.y, v0.y);
        m.z = fmaxf(m.z, v0.z); m.w = fmaxf(m.w, v0.w);
        if (d1 >= 0) {
          float4 v = *(const float4*)(emb + (size_t)d1 * 64 + 4 * l16);
          m.x = fmaxf(m.x, v.x); m.y = fmaxf(m.y, v.y);
          m.z = fmaxf(m.z, v.z); m.w = fmaxf(m.w, v.w);
        }
      }
      float4 s = {0.f, 0.f, 0.f, 0.f};
      for (int i = 0; i < n; i += 2) {
        int d0 = listB[o + i];
        int d1 = (i + 1 < n) ? listB[o + i + 1] : -1;
        float4 v0 = *(const float4*)(emb + (size_t)d0 * 64 + 4 * l16);
        s.x += __expf(v0.x - m.x); s.y += __expf(v0.y - m.y);
        s.z += __expf(v0.z - m.z); s.w += __expf(v0.w - m.w);
        if (d1 >= 0) {
          float4 v = *(const float4*)(emb + (size_t)d1 * 64 + 4 * l16);
          s.x += __expf(v.x - m.x); s.y += __expf(v.y - m.y);
          s.z += __expf(v.z - m.z); s.w += __expf(v.w - m.w);
        }
      }
      rx = __logf(s.x) + m.x; ry = __logf(s.y) + m.y;
      rz = __logf(s.z) + m.z; rw = __logf(s.w) + m.w;
    }
    lseH[(size_t)node * 16 + l16] = pack_h4(rx, ry, rz, rw);  // s >= 1 (max attained)
  }
}

// ======================= weight prep =======================
// Frag-ordered bf16 hi/lo. value = W[32s + 8*(lane>>4) + j][16c + (lane&15)].
// Elem offsets: l2c L1/L2/L3: 0/4096/8192; merge_W0: 12288 (K=128);
// merge_W L1/L2: 20480/24576; c2l L1/L2/L3: 28672/32768/36864. Total 40960.
__global__ void k_prepw(const float* __restrict__ l2cW, const float* __restrict__ mW0,
                        const float* __restrict__ mW, const float* __restrict__ c2lW,
                        unsigned short* __restrict__ WH, unsigned short* __restrict__ WL) {
  int tid = blockIdx.x * 256 + threadIdx.x;
  if (tid >= 40960) return;
  const float* src;
  int base;
  if (tid < 12288) {
    int m = tid / 4096; src = l2cW + m * 4096; base = m * 4096;
  } else if (tid < 20480) {
    src = mW0; base = 12288;
  } else if (tid < 28672) {
    int m = (tid - 20480) / 4096; src = mW + m * 4096; base = 20480 + m * 4096;
  } else {
    int m = (tid - 28672) / 4096; src = c2lW + m * 4096; base = 28672 + m * 4096;
  }
  int local = tid - base;
  int f = local >> 9;           // frag id = s*4+c
  int l = (local >> 3) & 63;    // lane
  int j = local & 7;            // elem
  int s = f >> 2, c = f & 3;
  int k = 32 * s + 8 * (l >> 4) + j;
  int col = 16 * c + (l & 15);
  float v = src[k * 64 + col];
  unsigned short hh = f2bf(v);
  WH[tid] = hh;
  WL[tid] = f2bf(v - bf2f(hh));
}

// ======================= MFMA MLP machinery =======================
// Wave-private LDS tile xs[16 rows][64 cols] f32, XOR-swizzled:
//   dword(row,col) = row*64 + (((col>>2) ^ row) & 15)*4 + (col & 3)
// 1024-thread blocks (16 waves): 80KB LDS -> 2 blocks/CU.

__device__ __forceinline__ void split8(float t0, float t1, float t2, float t3,
                                       float t4, float t5, float t6, float t7,
                                       bf16x8& ah, bf16x8& al) {
  unsigned short h;
  h = f2bf_hw(t0); ah[0] = (short)h; al[0] = (short)f2bf_hw(t0 - bf2f(h));
  h = f2bf_hw(t1); ah[1] = (short)h; al[1] = (short)f2bf_hw(t1 - bf2f(h));
  h = f2bf_hw(t2); ah[2] = (short)h; al[2] = (short)f2bf_hw(t2 - bf2f(h));
  h = f2bf_hw(t3); ah[3] = (short)h; al[3] = (short)f2bf_hw(t3 - bf2f(h));
  h = f2bf_hw(t4); ah[4] = (short)h; al[4] = (short)f2bf_hw(t4 - bf2f(h));
  h = f2bf_hw(t5); ah[5] = (short)h; al[5] = (short)f2bf_hw(t5 - bf2f(h));
  h = f2bf_hw(t6); ah[6] = (short)h; al[6] = (short)f2bf_hw(t6 - bf2f(h));
  h = f2bf_hw(t7); ah[7] = (short)h; al[7] = (short)f2bf_hw(t7 - bf2f(h));
}

// Stage one layer's 4096-elem hi+lo weights (16KB) with 1024 threads.
__device__ __forceinline__ void stage_w(const unsigned short* __restrict__ WH,
                                        const unsigned short* __restrict__ WL, int off,
                                        unsigned short* lwh, unsigned short* lwl, int tid) {
  __syncthreads();  // all waves done with previous layer's weights
  if (tid < 512) ((uint4*)lwh)[tid] = ((const uint4*)(WH + off))[tid];
  else           ((uint4*)lwl)[tid - 512] = ((const uint4*)(WL + off))[tid - 512];
  __syncthreads();
}

__device__ __forceinline__ void acc_init(const float* __restrict__ bias, int col15,
                                         f32x4 (&acc)[4]) {
#pragma unroll
  for (int c = 0; c < 4; ++c) {
    float bv = bias[16 * c + col15];
    acc[c] = (f32x4){bv, bv, bv, bv};
  }
}

__device__ __forceinline__ void acc_relu(f32x4 (&acc)[4]) {
#pragma unroll
  for (int c = 0; c < 4; ++c)
#pragma unroll
    for (int r = 0; r < 4; ++r) acc[c][r] = fmaxf(acc[c][r], 0.f);
}

// Accumulate 2 K-slices (K=64) from LDS weights. FLIPALL: partner row (t^1).
// Split-bf16: acc += al*wh + ah*wl + ah*wh (misses only lo*lo ~ 2^-18).
template <bool FLIPALL>
__device__ __forceinline__ void mfma_accum(const float* xw, int lane,
                                           const unsigned short* lwh,
                                           const unsigned short* lwl, f32x4 (&acc)[4]) {
  int col15 = lane & 15, hq = lane >> 4;
  int arow = FLIPALL ? (col15 ^ 1) : col15;
  const float* xr = xw + arow * 64;
#pragma unroll
  for (int s = 0; s < 2; ++s) {
    float4 A0 = *(const float4*)(xr + ((((8 * s + 2 * hq + 0) ^ arow) & 15) << 2));
    float4 A1 = *(const float4*)(xr + ((((8 * s + 2 * hq + 1) ^ arow) & 15) << 2));
    bf16x8 ah, al;
    split8(A0.x, A0.y, A0.z, A0.w, A1.x, A1.y, A1.z, A1.w, ah, al);
#pragma unroll
    for (int c = 0; c < 4; ++c) {
      bf16x8 wh = *(const bf16x8*)(lwh + ((s * 4 + c) * 64 + lane) * 8);
      bf16x8 wl = *(const bf16x8*)(lwl + ((s * 4 + c) * 64 + lane) * 8);
      acc[c] = __builtin_amdgcn_mfma_f32_16x16x32_bf16(al, wh, acc[c], 0, 0, 0);
      acc[c] = __builtin_amdgcn_mfma_f32_16x16x32_bf16(ah, wl, acc[c], 0, 0, 0);
      acc[c] = __builtin_amdgcn_mfma_f32_16x16x32_bf16(ah, wh, acc[c], 0, 0, 0);
    }
  }
}

__device__ __forceinline__ void commitA(float* xw, int lane, const f32x4 (&acc)[4]) {
  int col15 = lane & 15, hq = lane >> 4;
#pragma unroll
  for (int c = 0; c < 4; ++c)
#pragma unroll
    for (int r = 0; r < 4; ++r) {
      int row = 4 * hq + r, col = 16 * c + col15;
      xw[row * 64 + ((((col >> 2) ^ row) & 15) << 2) + (col & 3)] = acc[c][r];
    }
}

// ---- fused MLP kernel: blocks [0, nL) run l2c, blocks [nL, 2*nL) run c2l ----
__global__ void __launch_bounds__(1024, 8)
k_mlp(const int* __restrict__ ei, const int* __restrict__ l2ci, const int* __restrict__ c2li,
      const float* __restrict__ emb, const uint2* __restrict__ aggrH, const uint2* __restrict__ lseH,
      const unsigned short* __restrict__ WH, const unsigned short* __restrict__ WL,
      const float* __restrict__ l2cb, const float* __restrict__ mb0,
      const float* __restrict__ mb, const float* __restrict__ c2lb,
      float* __restrict__ out, int nL) {
  __shared__ float xs[16][1024];          // 64 KB
  __shared__ unsigned short lwh[4096];    // 8 KB
  __shared__ unsigned short lwl[4096];    // 8 KB
  int tid = threadIdx.x;
  int lane = tid & 63, w = tid >> 6;      // 16 waves
  float* xw = xs[w];
  bool isL = (int)blockIdx.x < nL;
  int bid = isL ? blockIdx.x : blockIdx.x - nL;
  const int* idx = isL ? l2ci : c2li;
  int rbase = (bid * 16 + w) * 16;
  int col15 = lane & 15, hq = lane >> 4;
  int rin = min(rbase + col15, HEDGE - 1);
  int j = idx[rin];
  int sN = ei[2 * j], dN = ei[2 * j + 1];
  const uint2* ap = (isL ? aggrH : lseH) + (size_t)sN * 16 + 4 * hq;
  const float* ep = emb + (size_t)dN * 64 + 16 * hq;
#pragma unroll
  for (int q = 0; q < 4; ++q) {
    float4 a = unpack_h4(ap[q]);
    float4 e = *(const float4*)(ep + 4 * q);
    float4 v = {a.x - e.x, a.y - e.y, a.z - e.z, a.w - e.w};
    *(float4*)(xw + col15 * 64 + ((((4 * hq + q) ^ col15) & 15) << 2)) = v;
  }
  f32x4 acc[4];
  if (isL) {
    stage_w(WH, WL, 0, lwh, lwl, tid);
    acc_init(l2cb, col15, acc);       mfma_accum<false>(xw, lane, lwh, lwl, acc);
    acc_relu(acc);                    commitA(xw, lane, acc);
    stage_w(WH, WL, 4096, lwh, lwl, tid);
    acc_init(l2cb + 64, col15, acc);  mfma_accum<false>(xw, lane, lwh, lwl, acc);
    acc_relu(acc);                    commitA(xw, lane, acc);
    stage_w(WH, WL, 8192, lwh, lwl, tid);
    acc_init(l2cb + 128, col15, acc); mfma_accum<false>(xw, lane, lwh, lwl, acc);
    commitA(xw, lane, acc);           // msg (no relu)
    stage_w(WH, WL, 12288, lwh, lwl, tid);   // merge own half
    acc_init(mb0, col15, acc);        mfma_accum<false>(xw, lane, lwh, lwl, acc);
    stage_w(WH, WL, 16384, lwh, lwl, tid);   // merge flip half
    mfma_accum<true>(xw, lane, lwh, lwl, acc);
    acc_relu(acc);                    commitA(xw, lane, acc);
    stage_w(WH, WL, 20480, lwh, lwl, tid);
    acc_init(mb, col15, acc);         mfma_accum<false>(xw, lane, lwh, lwl, acc);
    acc_relu(acc);                    commitA(xw, lane, acc);
    stage_w(WH, WL, 24576, lwh, lwl, tid);
    acc_init(mb + 64, col15, acc);    mfma_accum<false>(xw, lane, lwh, lwl, acc);
  } else {
    stage_w(WH, WL, 28672, lwh, lwl, tid);
    acc_init(c2lb, col15, acc);       mfma_accum<false>(xw, lane, lwh, lwl, acc);
    acc_relu(acc);                    commitA(xw, lane, acc);
    stage_w(WH, WL, 32768, lwh, lwl, tid);
    acc_init(c2lb + 64, col15, acc);  mfma_accum<false>(xw, lane, lwh, lwl, acc);
    acc_relu(acc);                    commitA(xw, lane, acc);
    stage_w(WH, WL, 36864, lwh, lwl, tid);
    acc_init(c2lb + 128, col15, acc); mfma_accum<false>(xw, lane, lwh, lwl, acc);
  }
  int jo[4];
#pragma unroll
  for (int r = 0; r < 4; ++r) {
    int rr = rbase + 4 * hq + r;
    jo[r] = (rr < HEDGE) ? idx[rr] : -1;
  }
#pragma unroll
  for (int c = 0; c < 4; ++c)
#pragma unroll
    for (int r = 0; r < 4; ++r)
      if (jo[r] >= 0) out[(size_t)jo[r] * 64 + 16 * c + col15] = acc[c][r];
}

extern "C" void kernel_launch(void* const* d_in, const int* in_sizes, int n_in,
                              void* d_out, int out_size, void* d_ws, size_t ws_size,
                              hipStream_t stream) {
  const int* ei = (const int*)d_in[0];
  const int* l2ci = (const int*)d_in[1];
  const int* c2li = (const int*)d_in[2];
  const float* emb = (const float*)d_in[3];
  const float* l2cW = (const float*)d_in[4];
  const float* l2cb = (const float*)d_in[5];
  const float* c2lW = (const float*)d_in[6];
  const float* c2lb = (const float*)d_in[7];
  const float* mW0 = (const float*)d_in[8];
  const float* mb0 = (const float*)d_in[9];
  const float* mW = (const float*)d_in[10];
  const float* mb = (const float*)d_in[11];
  float* out = (float*)d_out;

  char* ws = (char*)d_ws;
  const size_t NBH = (size_t)NNODE * 64 * 2;  // 25.6 MB per f16 node-buffer
  uint2* aggrH = (uint2*)ws;
  uint2* lseH = (uint2*)(ws + NBH);
  unsigned short* WH = (unsigned short*)(ws + 2 * NBH);
  unsigned short* WL = WH + 40960;  // 163840 B total for weights
  char* p = ws + 2 * NBH + 163840;
  int* degA = (int*)p; p += NNODE * 4;
  int* degB = (int*)p; p += NNODE * 4;
  int* cursors = (int*)p; p += 2 * 4;
  int* offA = (int*)p; p += NNODE * 4;
  int* offB = (int*)p; p += NNODE * 4;
  int* curA = (int*)p; p += NNODE * 4;
  int* curB = (int*)p; p += NNODE * 4;
  int* listA = (int*)p; p += (size_t)NEDGE * 4;
  int* listB = (int*)p; p += (size_t)HEDGE * 4;

  hipMemsetAsync(degA, 0, (2 * (size_t)NNODE + 2) * 4, stream);  // degA,degB,cursors

  dim3 B(256);
  int gE = (NEDGE + 255) / 256;
  k_deg<<<gE, B, 0, stream>>>(ei, c2li, degA, degB);
  k_alloc<<<(NNODE + 255) / 256, B, 0, stream>>>(degA, offA, curA, degB, offB, curB, cursors);
  k_fill<<<gE, B, 0, stream>>>(ei, c2li, curA, listA, curB, listB);
  k_prepw<<<160, B, 0, stream>>>(l2cW, mW0, mW, c2lW, WH, WL);
  int gNA = (NNODE + 31) / 32;  // task A: 32 nodes/block (8-lane groups)
  int gNB = (NNODE + 15) / 16;  // task B: 16 nodes/block (16-lane groups)
  k_gather<<<gNA + gNB, B, 0, stream>>>(offA, degA, listA, offB, degB, listB, emb, aggrH, lseH, gNA);
  int nL = (HEDGE + 255) / 256;  // 256 edges per 1024-thread block
  k_mlp<<<2 * nL, 1024, 0, stream>>>(ei, l2ci, c2li, emb, aggrH, lseH, WH, WL,
                                     l2cb, mb0, mb, c2lb, out, nL);
}